// Round 5
// baseline (187.133 us; speedup 1.0000x reference)
//
#include <hip/hip_runtime.h>
#include <stdint.h>

#define T_STEPS 32
#define DECAY   0.951229424500714f    // exp(-1/20)
#define DECAY16 0.449328964117222f    // exp(-16/20)

#define ROWS 16        // rows per block
#define KC   256       // k-chunk columns
#define NC   4         // chunks (K = 1024)

typedef __attribute__((ext_vector_type(4))) float f32x4;
typedef __attribute__((ext_vector_type(8))) short bf16x8;

__device__ __forceinline__ unsigned short f2bf(float f) {
    unsigned u = __builtin_bit_cast(unsigned, f);
    return (unsigned short)((u + 0x7FFFu + ((u >> 16) & 1u)) >> 16);
}

// W fp32 -> bf16 (2 MiB, L2/L3-resident afterwards)
__global__ __launch_bounds__(256) void wconv_kernel(
    const float* __restrict__ W, unsigned short* __restrict__ Wb)
{
    int idx = blockIdx.x * 256 + threadIdx.x;
    f32x4 v = ((const f32x4*)W)[idx];
    ushort4 o;
    o.x = f2bf(v.x); o.y = f2bf(v.y); o.z = f2bf(v.z); o.w = f2bf(v.w);
    ((ushort4*)Wb)[idx] = o;
}

// Fused temporal-reduce + GEMM. Block owns 16 rows; 8 waves, wave owns 128 cols.
// Per k-chunk: reduce x (HBM, nt) -> regs -> swizzled LDS bf16; MFMA vs W (L2).
// MFMA of chunk c overlaps the t-loop of chunk c+1; one barrier per chunk.
__global__ __launch_bounds__(512) void fused_kernel(
    const float* __restrict__ x, const unsigned short* __restrict__ Wb,
    const float* __restrict__ bias, float* __restrict__ C,
    int N, int K)
{
    __shared__ unsigned short Asw[2][ROWS][KC];   // 2 x 8 KiB, XOR-swizzled rows

    int tid  = threadIdx.x;
    int lane = tid & 63;
    int w    = tid >> 6;                 // wave 0..7
    int r0   = blockIdx.x * ROWS;

    const size_t rowstr = (size_t)T_STEPS * K;          // x row stride (floats)
    const float* x0 = x + (size_t)(r0 + w)     * rowstr + lane * 4;   // row w
    const float* x1 = x + (size_t)(r0 + 8 + w) * rowstr + lane * 4;   // row 8+w

    // LDS write offsets. Swizzle: byte_in_row ^= (row&7)<<4; row&7 == w for both.
    char* ldsbase = (char*)&Asw[0][0][0];
    int sw  = (w & 7) << 4;
    int st0 = (w)     * (KC * 2) + ((lane * 8) ^ sw);
    int st1 = (8 + w) * (KC * 2) + ((lane * 8) ^ sw);

    int fr  = lane & 15;                 // fragment row (A: m, B: n)
    int q16 = lane >> 4;                 // 0..3 quarter-wave (k offset)

    f32x4 accC[8] = {};                  // C frags: 8 n-frags x 16 rows

    ushort4 o0, o1;                      // reduced+packed chunk rows (bf16x4)
    auto tloop = [&](int c) {
        const float* p0 = x0 + c * KC;
        const float* p1 = x1 + c * KC;
        f32x4 h0 = {0.f,0.f,0.f,0.f}, l0 = {0.f,0.f,0.f,0.f};
        f32x4 h1 = {0.f,0.f,0.f,0.f}, l1 = {0.f,0.f,0.f,0.f};
        #pragma unroll
        for (int t = 0; t < 16; ++t) {   // two 16-chains per row for ILP
            f32x4 a = __builtin_nontemporal_load((const f32x4*)(p0 + (size_t)t * K));
            f32x4 b = __builtin_nontemporal_load((const f32x4*)(p0 + (size_t)(t + 16) * K));
            f32x4 e = __builtin_nontemporal_load((const f32x4*)(p1 + (size_t)t * K));
            f32x4 d = __builtin_nontemporal_load((const f32x4*)(p1 + (size_t)(t + 16) * K));
            h0 = h0 * DECAY + a;  l0 = l0 * DECAY + b;
            h1 = h1 * DECAY + e;  l1 = l1 * DECAY + d;
        }
        f32x4 r0v = h0 * DECAY16 + l0;
        f32x4 r1v = h1 * DECAY16 + l1;
        o0.x = f2bf(r0v.x); o0.y = f2bf(r0v.y); o0.z = f2bf(r0v.z); o0.w = f2bf(r0v.w);
        o1.x = f2bf(r1v.x); o1.y = f2bf(r1v.y); o1.z = f2bf(r1v.z); o1.w = f2bf(r1v.w);
    };
    auto stA = [&](int b) {
        char* base = ldsbase + b * (ROWS * KC * 2);
        *(ushort4*)(base + st0) = o0;
        *(ushort4*)(base + st1) = o1;
    };

    tloop(0);
    stA(0);
    __syncthreads();

    #pragma unroll
    for (int c = 0; c < NC; ++c) {
        if (c < NC - 1) tloop(c + 1);    // HBM stream for next chunk (overlaps MFMA)

        // MFMA chunk c from LDS buf c&1 (a-frags), W b-frags direct from L2
        const char* abase = ldsbase + (c & 1) * (ROWS * KC * 2) + fr * (KC * 2);
        int frx = (fr & 7) << 4;
        bf16x8 af[8];
        #pragma unroll
        for (int kf = 0; kf < 8; ++kf)
            af[kf] = *(const bf16x8*)(abase + ((kf * 64 + q16 * 16) ^ frx));

        #pragma unroll
        for (int nf = 0; nf < 8; ++nf) {
            const unsigned short* wp =
                Wb + (size_t)(w * 128 + nf * 16 + fr) * K + c * KC + q16 * 8;
            #pragma unroll
            for (int kf = 0; kf < 8; ++kf) {
                bf16x8 bfr = *(const bf16x8*)(wp + kf * 32);
                accC[nf] = __builtin_amdgcn_mfma_f32_16x16x32_bf16(af[kf], bfr, accC[nf], 0, 0, 0);
            }
        }

        // 2-buffer safety: writer of buf (c+1)&1 is past ITS MFMA_c; any wave
        // that could still read that buf (MFMA_{c-1}) is pre-barrier of iter c-1,
        // which this wave already passed. One barrier per chunk suffices.
        if (c < NC - 1) {
            stA((c + 1) & 1);
            __syncthreads();
        }
    }

    // epilogue: C/D layout col = lane&15, row = (lane>>4)*4 + reg
    int fq = q16 * 4;
    #pragma unroll
    for (int nf = 0; nf < 8; ++nf) {
        int col = w * 128 + nf * 16 + fr;
        float bv = bias[col];
        #pragma unroll
        for (int r = 0; r < 4; ++r) {
            int row = r0 + fq + r;
            C[(size_t)row * N + col] = accC[nf][r] + bv;
        }
    }
}

extern "C" void kernel_launch(void* const* d_in, const int* in_sizes, int n_in,
                              void* d_out, int out_size, void* d_ws, size_t ws_size,
                              hipStream_t stream) {
    const float* x    = (const float*)d_in[0];
    const float* W    = (const float*)d_in[1];
    const float* bias = (const float*)d_in[2];
    float* out = (float*)d_out;

    int Dout = in_sizes[2];                   // 1024
    int Din  = in_sizes[1] / Dout;            // 1024
    int M    = in_sizes[0] / (T_STEPS * Din); // 4096 (= B*S)

    unsigned short* Wb = (unsigned short*)d_ws;   // Dout*Din bf16 (2 MiB)

    int wBlocks = (Dout * Din) / (4 * 256);   // 1024
    wconv_kernel<<<wBlocks, 256, 0, stream>>>(W, Wb);

    int grid = M / ROWS;                      // 256
    fused_kernel<<<grid, 512, 0, stream>>>(x, Wb, bias, out, Dout, Din);
}

// Round 6
// 113.431 us; speedup vs baseline: 1.6498x; 1.6498x over previous
//
#include <hip/hip_runtime.h>
#include <stdint.h>

#define T_STEPS 32
#define DECAY   0.951229424500714f    // exp(-1/20)
#define DECAY16 0.449328964117222f    // exp(-16/20)

typedef __attribute__((ext_vector_type(4))) float f32x4;
typedef __attribute__((ext_vector_type(8))) short bf16x8;

typedef const void __attribute__((address_space(1)))* gptr_t;
typedef void __attribute__((address_space(3)))* sptr_t;

__device__ __forceinline__ unsigned short f2bf(float f) {
    unsigned u = __builtin_bit_cast(unsigned, f);
    return (unsigned short)((u + 0x7FFFu + ((u >> 16) & 1u)) >> 16);
}

// blocks [0, mBlocks): temporal leaky reduce x[M][T][D] -> mem[M][D] (bf16 bits)
// blocks [mBlocks, ...): convert W fp32 -> bf16
// (byte-identical to R3's prep — any total delta this round is the GEMM)
__global__ __launch_bounds__(256) void prep_kernel(
    const float* __restrict__ x, const float* __restrict__ W,
    unsigned short* __restrict__ mem, unsigned short* __restrict__ Wb,
    int mBlocks, int M, int D)
{
    if ((int)blockIdx.x < mBlocks) {
        int idx = blockIdx.x * 256 + threadIdx.x;   // one per 4 floats of mem
        int perRow = D >> 2;                        // float4 per row
        int m = idx / perRow;
        int d4 = idx - m * perRow;
        if (m >= M) return;
        const f32x4* xr = (const f32x4*)(x + (size_t)m * T_STEPS * D) + d4;
        // two independent 16-long chains for load ILP; result = hi*d^16 + lo
        f32x4 accH = {0.f, 0.f, 0.f, 0.f};
        f32x4 accL = {0.f, 0.f, 0.f, 0.f};
        #pragma unroll
        for (int t = 0; t < 16; ++t) {
            f32x4 vh = __builtin_nontemporal_load(&xr[(size_t)t * perRow]);
            f32x4 vl = __builtin_nontemporal_load(&xr[(size_t)(t + 16) * perRow]);
            accH = accH * DECAY + vh;
            accL = accL * DECAY + vl;
        }
        f32x4 acc = accH * DECAY16 + accL;
        ushort4 o;
        o.x = f2bf(acc.x); o.y = f2bf(acc.y); o.z = f2bf(acc.z); o.w = f2bf(acc.w);
        *(ushort4*)(mem + (size_t)idx * 4) = o;
    } else {
        int idx = (blockIdx.x - mBlocks) * 256 + threadIdx.x;
        f32x4 v = ((const f32x4*)W)[idx];
        ushort4 o;
        o.x = f2bf(v.x); o.y = f2bf(v.y); o.z = f2bf(v.z); o.w = f2bf(v.w);
        *(ushort4*)(Wb + (size_t)idx * 4) = o;
    }
}

// C[M][N] = A[M][K] @ B[N][K]^T + bias, bf16 inputs, fp32 out
// 64x128 tile, BK=32, 4 waves (2x2), wave tile 32x64.
// Quad-buffered LDS, depth-3 prefetch, counted vmcnt(6) (never 0 mid-loop).
#define BM 64
#define BN 128
#define BK 32

__global__ __launch_bounds__(256) void gemm_kernel(
    const unsigned short* __restrict__ A,    // mem bf16 [M][K]
    const unsigned short* __restrict__ Bw,   // W bf16 [N][K]
    const float* __restrict__ bias,          // [N]
    float* __restrict__ C,                   // [M][N]
    int M, int N, int K)
{
    __shared__ unsigned short As[4][BM][BK];   // 4 x 4 KiB
    __shared__ unsigned short Bs[4][BN][BK];   // 4 x 8 KiB   (48 KiB total)

    // XCD-aware swizzle (grid=512, 512%8==0 -> bijective)
    int nwg = gridDim.x;
    int cpx = nwg >> 3;
    int bid = (int)blockIdx.x;
    int wg  = (bid & 7) * cpx + (bid >> 3);

    int nbn = N / BN;
    int bm = wg / nbn;
    int bn = wg % nbn;

    int tid  = threadIdx.x;
    int lane = tid & 63;
    int wid  = tid >> 6;         // 0..3
    int wr   = wid >> 1;         // wave row block (32 rows)
    int wc   = wid & 1;          // wave col block (64 cols)

    // staging: LDS dest byte = 16*tid within each chunk (linear, rule 21)
    int srow = tid >> 2;         // 0..63
    int scol = (tid & 3) << 3;   // bf16 elems 0,8,16,24

    const unsigned short* Ag  = A  + (size_t)(bm * BM + srow) * K + scol;
    const unsigned short* Bg0 = Bw + (size_t)(bn * BN + srow) * K + scol;
    const unsigned short* Bg1 = Bw + (size_t)(bn * BN + 64 + srow) * K + scol;

    f32x4 acc[2][4] = {};

    int fr = lane & 15;          // row within 16x16 fragment
    int fk = (lane >> 4) << 3;   // k offset (8 bf16 per lane)

    auto stage = [&](int b, int kt) {
        int k0 = kt * BK;
        __builtin_amdgcn_global_load_lds((gptr_t)(Ag  + k0), (sptr_t)(&As[b][srow][scol]),      16, 0, 0);
        __builtin_amdgcn_global_load_lds((gptr_t)(Bg0 + k0), (sptr_t)(&Bs[b][srow][scol]),      16, 0, 0);
        __builtin_amdgcn_global_load_lds((gptr_t)(Bg1 + k0), (sptr_t)(&Bs[b][64 + srow][scol]), 16, 0, 0);
    };

    int nk = K / BK;             // 32

    stage(0, 0);
    stage(1, 1);
    stage(2, 2);                                       // 9 loads outstanding
    asm volatile("s_waitcnt vmcnt(6)" ::: "memory");   // buf0 landed
    __builtin_amdgcn_s_barrier();

    for (int kt = 0; kt < nk; ++kt) {
        int cur = kt & 3;
        if (kt + 3 < nk) stage((kt + 3) & 3, kt + 3);   // keep pipeline 3 deep

        bf16x8 a0 = *(const bf16x8*)&As[cur][wr * 32 +      fr][fk];
        bf16x8 a1 = *(const bf16x8*)&As[cur][wr * 32 + 16 + fr][fk];
        bf16x8 b0 = *(const bf16x8*)&Bs[cur][wc * 64 +      fr][fk];
        bf16x8 b1 = *(const bf16x8*)&Bs[cur][wc * 64 + 16 + fr][fk];
        bf16x8 b2 = *(const bf16x8*)&Bs[cur][wc * 64 + 32 + fr][fk];
        bf16x8 b3 = *(const bf16x8*)&Bs[cur][wc * 64 + 48 + fr][fk];

        acc[0][0] = __builtin_amdgcn_mfma_f32_16x16x32_bf16(a0, b0, acc[0][0], 0, 0, 0);
        acc[0][1] = __builtin_amdgcn_mfma_f32_16x16x32_bf16(a0, b1, acc[0][1], 0, 0, 0);
        acc[0][2] = __builtin_amdgcn_mfma_f32_16x16x32_bf16(a0, b2, acc[0][2], 0, 0, 0);
        acc[0][3] = __builtin_amdgcn_mfma_f32_16x16x32_bf16(a0, b3, acc[0][3], 0, 0, 0);
        acc[1][0] = __builtin_amdgcn_mfma_f32_16x16x32_bf16(a1, b0, acc[1][0], 0, 0, 0);
        acc[1][1] = __builtin_amdgcn_mfma_f32_16x16x32_bf16(a1, b1, acc[1][1], 0, 0, 0);
        acc[1][2] = __builtin_amdgcn_mfma_f32_16x16x32_bf16(a1, b2, acc[1][2], 0, 0, 0);
        acc[1][3] = __builtin_amdgcn_mfma_f32_16x16x32_bf16(a1, b3, acc[1][3], 0, 0, 0);

        // wait until buf kt+1's stage has landed; never drain to 0 mid-loop
        if (kt + 3 < nk) {
            asm volatile("s_waitcnt vmcnt(6)" ::: "memory");   // stages kt+2,kt+3 may fly
        } else if (kt + 2 < nk) {
            asm volatile("s_waitcnt vmcnt(3)" ::: "memory");
        } else if (kt + 1 < nk) {
            asm volatile("s_waitcnt vmcnt(0)" ::: "memory");
        }
        if (kt + 1 < nk) __builtin_amdgcn_s_barrier();
    }

    // C/D layout: col = lane&15, row = (lane>>4)*4 + reg
    int fc  = lane & 15;
    int fq  = (lane >> 4) << 2;
    int row0 = bm * BM + wr * 32;
    int col0 = bn * BN + wc * 64;
    #pragma unroll
    for (int mi = 0; mi < 2; ++mi) {
        #pragma unroll
        for (int ni = 0; ni < 4; ++ni) {
            int col = col0 + ni * 16 + fc;
            float bv = bias[col];
            #pragma unroll
            for (int r = 0; r < 4; ++r) {
                int row = row0 + mi * 16 + fq + r;
                __builtin_nontemporal_store(acc[mi][ni][r] + bv, &C[(size_t)row * N + col]);
            }
        }
    }
}

extern "C" void kernel_launch(void* const* d_in, const int* in_sizes, int n_in,
                              void* d_out, int out_size, void* d_ws, size_t ws_size,
                              hipStream_t stream) {
    const float* x    = (const float*)d_in[0];
    const float* W    = (const float*)d_in[1];
    const float* bias = (const float*)d_in[2];
    float* out = (float*)d_out;

    int Dout = in_sizes[2];                   // 1024
    int Din  = in_sizes[1] / Dout;            // 1024
    int M    = in_sizes[0] / (T_STEPS * Din); // 4096 (= B*S)

    unsigned short* mem = (unsigned short*)d_ws;                      // M*Din bf16
    unsigned short* Wb  = (unsigned short*)d_ws + (size_t)M * Din;    // Dout*Din bf16

    int mBlocks = (M * Din) / (4 * 256);      // 4096
    int wBlocks = (Dout * Din) / (4 * 256);   // 1024
    prep_kernel<<<mBlocks + wBlocks, 256, 0, stream>>>(x, W, mem, Wb, mBlocks, M, Din);

    int grid = (M / BM) * (Dout / BN);        // 512
    gemm_kernel<<<grid, 256, 0, stream>>>(mem, Wb, bias, out, M, Dout, Din);
}